// Round 12
// baseline (495.059 us; speedup 1.0000x reference)
//
#include <hip/hip_runtime.h>
#include <stdint.h>

// RecursiveLSTM: B=1024 seqs, T=96, H=50, num_pred=12.  Wave-per-sequence.
// ROUND-12: 3-way pass lockstep (p,p+1,p+2 interleaved per iter; 4 trios),
// weights+bias+W_ih fused into 52-wide rows held in v48..v255 (208 regs,
// loaded ONCE), h_ext=[1,xv,h0..h49] in LDS per pass, shared 4-buffer
// ds_read_b128 rotation (read-ahead ~3 groups), serialized 6-solo epilogue
// per trio for the pred-dependency chain.  r11 counters: 1310/2115 cyc
// busy per dual-iter -> ~800 idle; third chain + deeper rotation fills it.
//
// Register map: v0-15 staging(4xb128) | v16-18 c_A/B/C | v19 xa(xbuf ptr)
// v20 lds base (h_A@0,h_B@256,h_C@512,xbuf@768) | v21 lane hn-write addr
// v22-29/30-37/38-45 accs A/B/C | v46 wfc | v47 free(operand) | v48+ weights
// (i:48-99 f:100-151 g:152-203 o:204-255; pair0=(bias,W_ih))

#define HSZ 50
#define TLEN 96

#define GRP(WT,A0,A1,A2,A3,IL,IH,FL,FH,GL,GH,OL,OH,BL,BH,POST) \
    "s_waitcnt lgkmcnt(" WT ")\n\t" \
    "v_pk_fma_f32 v[" A0 "], v[" IL "], v[" BL "], v[" A0 "]\n\t" \
    "v_pk_fma_f32 v[" A1 "], v[" FL "], v[" BL "], v[" A1 "]\n\t" \
    "v_pk_fma_f32 v[" A2 "], v[" GL "], v[" BL "], v[" A2 "]\n\t" \
    "v_pk_fma_f32 v[" A3 "], v[" OL "], v[" BL "], v[" A3 "]\n\t" \
    "v_pk_fma_f32 v[" A0 "], v[" IH "], v[" BH "], v[" A0 "]\n\t" \
    "v_pk_fma_f32 v[" A1 "], v[" FH "], v[" BH "], v[" A1 "]\n\t" \
    "v_pk_fma_f32 v[" A2 "], v[" GH "], v[" BH "], v[" A2 "]\n\t" \
    "v_pk_fma_f32 v[" A3 "], v[" OH "], v[" BH "], v[" A3 "]\n\t" \
    POST

// m=0 variant: pk_mul inits the accumulators (bias+x folded into pair 0)
#define GRPM(WT,A0,A1,A2,A3,IL,IH,FL,FH,GL,GH,OL,OH,BL,BH,POST) \
    "s_waitcnt lgkmcnt(" WT ")\n\t" \
    "v_pk_mul_f32 v[" A0 "], v[" IL "], v[" BL "]\n\t" \
    "v_pk_mul_f32 v[" A1 "], v[" FL "], v[" BL "]\n\t" \
    "v_pk_mul_f32 v[" A2 "], v[" GL "], v[" BL "]\n\t" \
    "v_pk_mul_f32 v[" A3 "], v[" OL "], v[" BL "]\n\t" \
    "v_pk_fma_f32 v[" A0 "], v[" IH "], v[" BH "], v[" A0 "]\n\t" \
    "v_pk_fma_f32 v[" A1 "], v[" FH "], v[" BH "], v[" A1 "]\n\t" \
    "v_pk_fma_f32 v[" A2 "], v[" GH "], v[" BH "], v[" A2 "]\n\t" \
    "v_pk_fma_f32 v[" A3 "], v[" OH "], v[" BH "], v[" A3 "]\n\t" \
    POST

#define GRPX(...)  GRP(__VA_ARGS__)
#define GRPMX(...) GRPM(__VA_ARGS__)
#define SOLOX(...) SOLO(__VA_ARGS__)

// acc-pair strings per pass
#define PA "22:23","24:25","26:27","28:29"
#define PB "30:31","32:33","34:35","36:37"
#define PC "38:39","40:41","42:43","44:45"
// weight-pair strings per m (i,f,g,o bases 48/100/152/204, +4m)
#define W0  "48:49","50:51","100:101","102:103","152:153","154:155","204:205","206:207"
#define W1  "52:53","54:55","104:105","106:107","156:157","158:159","208:209","210:211"
#define W2  "56:57","58:59","108:109","110:111","160:161","162:163","212:213","214:215"
#define W3  "60:61","62:63","112:113","114:115","164:165","166:167","216:217","218:219"
#define W4  "64:65","66:67","116:117","118:119","168:169","170:171","220:221","222:223"
#define W5  "68:69","70:71","120:121","122:123","172:173","174:175","224:225","226:227"
#define W6  "72:73","74:75","124:125","126:127","176:177","178:179","228:229","230:231"
#define W7  "76:77","78:79","128:129","130:131","180:181","182:183","232:233","234:235"
#define W8  "80:81","82:83","132:133","134:135","184:185","186:187","236:237","238:239"
#define W9  "84:85","86:87","136:137","138:139","188:189","190:191","240:241","242:243"
#define W10 "88:89","90:91","140:141","142:143","192:193","194:195","244:245","246:247"
#define W11 "92:93","94:95","144:145","146:147","196:197","198:199","248:249","250:251"
#define W12 "96:97","98:99","148:149","150:151","200:201","202:203","252:253","254:255"
// staging-buffer pair strings
#define B0 "0:1","2:3"
#define B1 "4:5","6:7"
#define B2 "8:9","10:11"
#define B3 "12:13","14:15"

// solo step for one pass: set xv, 13 groups (2-buf rotation), tail, write hn
#define SOLO(XOFF,XW,CR,HNW,H0,H1,H2,H3,H4,H5,H6,H7,H8,H9,H10,H11,H12) \
    "ds_read_b32 v12, v19 offset:" XOFF "\n\t" \
    "s_waitcnt lgkmcnt(0)\n\t" \
    "ds_write_b32 v20, v12 offset:" XW "\n\t" \
    "ds_read_b128 v[0:3], v20 offset:" H0 "\n\t" \
    "ds_read_b128 v[4:7], v20 offset:" H1 "\n\t" \
    GRPMX("1", PA, W0, B0, "ds_read_b128 v[0:3], v20 offset:" H2 "\n\t") \
    GRPX("1", PA, W1,  B1, "ds_read_b128 v[4:7], v20 offset:" H3 "\n\t") \
    GRPX("1", PA, W2,  B0, "ds_read_b128 v[0:3], v20 offset:" H4 "\n\t") \
    GRPX("1", PA, W3,  B1, "ds_read_b128 v[4:7], v20 offset:" H5 "\n\t") \
    GRPX("1", PA, W4,  B0, "ds_read_b128 v[0:3], v20 offset:" H6 "\n\t") \
    GRPX("1", PA, W5,  B1, "ds_read_b128 v[4:7], v20 offset:" H7 "\n\t") \
    GRPX("1", PA, W6,  B0, "ds_read_b128 v[0:3], v20 offset:" H8 "\n\t") \
    GRPX("1", PA, W7,  B1, "ds_read_b128 v[4:7], v20 offset:" H9 "\n\t") \
    GRPX("1", PA, W8,  B0, "ds_read_b128 v[0:3], v20 offset:" H10 "\n\t") \
    GRPX("1", PA, W9,  B1, "ds_read_b128 v[4:7], v20 offset:" H11 "\n\t") \
    GRPX("1", PA, W10, B0, "ds_read_b128 v[0:3], v20 offset:" H12 "\n\t") \
    GRPX("1", PA, W11, B1, "") \
    GRPX("0", PA, W12, B0, "") \
    "v_add_f32 v22, v22, v23\n\t" \
    "v_add_f32 v24, v24, v25\n\t" \
    "v_add_f32 v26, v26, v27\n\t" \
    "v_add_f32 v28, v28, v29\n\t" \
    "v_mul_f32 v23, 0xbfb8aa3b, v22\n\t" \
    "v_mul_f32 v25, 0xbfb8aa3b, v24\n\t" \
    "v_mul_f32 v27, 0x4038aa3b, v26\n\t" \
    "v_mul_f32 v29, 0xbfb8aa3b, v28\n\t" \
    "v_exp_f32 v23, v23\n\t" "v_exp_f32 v25, v25\n\t" \
    "v_exp_f32 v27, v27\n\t" "v_exp_f32 v29, v29\n\t" \
    "v_add_f32 v23, 1.0, v23\n\t" "v_add_f32 v25, 1.0, v25\n\t" \
    "v_add_f32 v27, 1.0, v27\n\t" "v_add_f32 v29, 1.0, v29\n\t" \
    "v_rcp_f32 v23, v23\n\t" "v_rcp_f32 v25, v25\n\t" \
    "v_rcp_f32 v27, v27\n\t" "v_rcp_f32 v29, v29\n\t" \
    "s_nop 1\n\t" \
    "v_fma_f32 v27, -2.0, v27, 1.0\n\t" \
    "v_mul_f32 v22, v23, v27\n\t" \
    "v_fma_f32 " CR ", v25, " CR ", v22\n\t" \
    "v_mul_f32 v24, 0x4038aa3b, " CR "\n\t" \
    "v_exp_f32 v24, v24\n\t" \
    "s_nop 1\n\t" \
    "v_add_f32 v24, 1.0, v24\n\t" \
    "v_rcp_f32 v24, v24\n\t" \
    "s_nop 1\n\t" \
    "v_fma_f32 v24, -2.0, v24, 1.0\n\t" \
    "v_mul_f32 v22, v29, v24\n\t" \
    "ds_write_b32 v21, v22 offset:" HNW "\n\t"

#define HA "0","16","32","48","64","80","96","112","128","144","160","176","192"
#define HB "256","272","288","304","320","336","352","368","384","400","416","432","448"
#define HC "512","528","544","560","576","592","608","624","640","656","672","688","704"

// FC head: hn(v22)*wfc(v46) butterfly-reduced; + bfc(s25); pred -> xbuf
#define FC(PREDOFF) \
    "v_mul_f32 v26, v22, v46\n\t" \
    "s_nop 1\n\t" \
    "ds_swizzle_b32 v27, v26 offset:0x041F\n\t" \
    "s_waitcnt lgkmcnt(0)\n\t" \
    "v_add_f32 v26, v26, v27\n\t" \
    "ds_swizzle_b32 v27, v26 offset:0x081F\n\t" \
    "s_waitcnt lgkmcnt(0)\n\t" \
    "v_add_f32 v26, v26, v27\n\t" \
    "ds_swizzle_b32 v27, v26 offset:0x101F\n\t" \
    "s_waitcnt lgkmcnt(0)\n\t" \
    "v_add_f32 v26, v26, v27\n\t" \
    "ds_swizzle_b32 v27, v26 offset:0x201F\n\t" \
    "s_waitcnt lgkmcnt(0)\n\t" \
    "v_add_f32 v26, v26, v27\n\t" \
    "ds_swizzle_b32 v27, v26 offset:0x401F\n\t" \
    "s_waitcnt lgkmcnt(0)\n\t" \
    "v_add_f32 v26, v26, v27\n\t" \
    "s_nop 1\n\t" \
    "v_readlane_b32 s26, v26, 0\n\t" \
    "v_readlane_b32 s27, v26, 32\n\t" \
    "s_nop 4\n\t" \
    "v_mov_b32 v27, s26\n\t" \
    "v_add_f32 v27, s27, v27\n\t" \
    "v_add_f32 v27, s25, v27\n\t" \
    "ds_write_b32 v19, v27 offset:" PREDOFF "\n\t"

__global__ __attribute__((amdgpu_flat_work_group_size(64, 64),
                          amdgpu_waves_per_eu(1, 1)))
void rec_lstm_kernel(const float* __restrict__ x,
                     const float* __restrict__ W_ih,
                     const float* __restrict__ W_hh,
                     const float* __restrict__ b_ih,
                     const float* __restrict__ b_hh,
                     const float* __restrict__ W_fc,
                     const float* __restrict__ b_fc,
                     const int*   __restrict__ num_pred,
                     float*       __restrict__ out)
{
    const int b = blockIdx.x;
    const int j = threadIdx.x;

    // LDS: h_A @0 (64f), h_B @256B, h_C @512B, xbuf @768B (112 floats)
    __shared__ __align__(16) float lds[304];
    if (j < 48) { lds[192 + j] = x[b*TLEN + j]; lds[192 + j + 48] = x[b*TLEN + j + 48]; }

    const int NP = num_pred[0];
    const int nt = NP / 3;                 // reference NP = 12 -> 4 trios
    const uint32_t lb = (uint32_t)(uintptr_t)&lds[0];

    asm volatile(
        // ================= once: consts, lane calc, weight load =========
        "s_load_dword s25, %[bfcp], 0x0\n\t"
        "s_waitcnt lgkmcnt(0)\n\t"
        "v_mbcnt_lo_u32_b32 v0, -1, 0\n\t"
        "v_mbcnt_hi_u32_b32 v0, -1, v0\n\t"
        "s_mov_b32 s22, 49\n\t"
        "v_min_u32 v1, s22, v0\n\t"               // u = min(lane,49)
        "s_mov_b32 s22, 200\n\t"
        "v_mul_lo_u32 v2, s22, v1\n\t"            // i-row byte off
        "s_mov_b32 s22, 10000\n\t"
        "v_add_u32 v3, s22, v2\n\t"               // f-row
        "s_mov_b32 s22, 20000\n\t"
        "v_add_u32 v4, s22, v2\n\t"               // g-row
        "s_mov_b32 s22, 30000\n\t"
        "v_add_u32 v5, s22, v2\n\t"               // o-row
        "v_lshlrev_b32 v6, 2, v1\n\t"             // u*4
        // biases / W_ih / wfc
        "global_load_dword v48,  v6, %[bih]\n\t"
        "global_load_dword v100, v6, %[bih] offset:200\n\t"
        "global_load_dword v152, v6, %[bih] offset:400\n\t"
        "global_load_dword v204, v6, %[bih] offset:600\n\t"
        "global_load_dword v7,  v6, %[bhh]\n\t"
        "global_load_dword v8,  v6, %[bhh] offset:200\n\t"
        "global_load_dword v9,  v6, %[bhh] offset:400\n\t"
        "global_load_dword v10, v6, %[bhh] offset:600\n\t"
        "global_load_dword v49,  v6, %[wih]\n\t"
        "global_load_dword v101, v6, %[wih] offset:200\n\t"
        "global_load_dword v153, v6, %[wih] offset:400\n\t"
        "global_load_dword v205, v6, %[wih] offset:600\n\t"
        "global_load_dword v46, v6, %[wfcp]\n\t"
        // W_hh rows (50 each): i -> v50.., f -> v102.., g -> v154.., o -> v206..
        "global_load_dwordx4 v[50:53], v2, %[whh]\n\t"
        "global_load_dwordx4 v[54:57], v2, %[whh] offset:16\n\t"
        "global_load_dwordx4 v[58:61], v2, %[whh] offset:32\n\t"
        "global_load_dwordx4 v[62:65], v2, %[whh] offset:48\n\t"
        "global_load_dwordx4 v[66:69], v2, %[whh] offset:64\n\t"
        "global_load_dwordx4 v[70:73], v2, %[whh] offset:80\n\t"
        "global_load_dwordx4 v[74:77], v2, %[whh] offset:96\n\t"
        "global_load_dwordx4 v[78:81], v2, %[whh] offset:112\n\t"
        "global_load_dwordx4 v[82:85], v2, %[whh] offset:128\n\t"
        "global_load_dwordx4 v[86:89], v2, %[whh] offset:144\n\t"
        "global_load_dwordx4 v[90:93], v2, %[whh] offset:160\n\t"
        "global_load_dwordx4 v[94:97], v2, %[whh] offset:176\n\t"
        "global_load_dwordx2 v[98:99], v2, %[whh] offset:192\n\t"
        "global_load_dwordx4 v[102:105], v3, %[whh]\n\t"
        "global_load_dwordx4 v[106:109], v3, %[whh] offset:16\n\t"
        "global_load_dwordx4 v[110:113], v3, %[whh] offset:32\n\t"
        "global_load_dwordx4 v[114:117], v3, %[whh] offset:48\n\t"
        "global_load_dwordx4 v[118:121], v3, %[whh] offset:64\n\t"
        "global_load_dwordx4 v[122:125], v3, %[whh] offset:80\n\t"
        "global_load_dwordx4 v[126:129], v3, %[whh] offset:96\n\t"
        "global_load_dwordx4 v[130:133], v3, %[whh] offset:112\n\t"
        "global_load_dwordx4 v[134:137], v3, %[whh] offset:128\n\t"
        "global_load_dwordx4 v[138:141], v3, %[whh] offset:144\n\t"
        "global_load_dwordx4 v[142:145], v3, %[whh] offset:160\n\t"
        "global_load_dwordx4 v[146:149], v3, %[whh] offset:176\n\t"
        "global_load_dwordx2 v[150:151], v3, %[whh] offset:192\n\t"
        "global_load_dwordx4 v[154:157], v4, %[whh]\n\t"
        "global_load_dwordx4 v[158:161], v4, %[whh] offset:16\n\t"
        "global_load_dwordx4 v[162:165], v4, %[whh] offset:32\n\t"
        "global_load_dwordx4 v[166:169], v4, %[whh] offset:48\n\t"
        "global_load_dwordx4 v[170:173], v4, %[whh] offset:64\n\t"
        "global_load_dwordx4 v[174:177], v4, %[whh] offset:80\n\t"
        "global_load_dwordx4 v[178:181], v4, %[whh] offset:96\n\t"
        "global_load_dwordx4 v[182:185], v4, %[whh] offset:112\n\t"
        "global_load_dwordx4 v[186:189], v4, %[whh] offset:128\n\t"
        "global_load_dwordx4 v[190:193], v4, %[whh] offset:144\n\t"
        "global_load_dwordx4 v[194:197], v4, %[whh] offset:160\n\t"
        "global_load_dwordx4 v[198:201], v4, %[whh] offset:176\n\t"
        "global_load_dwordx2 v[202:203], v4, %[whh] offset:192\n\t"
        "global_load_dwordx4 v[206:209], v5, %[whh]\n\t"
        "global_load_dwordx4 v[210:213], v5, %[whh] offset:16\n\t"
        "global_load_dwordx4 v[214:217], v5, %[whh] offset:32\n\t"
        "global_load_dwordx4 v[218:221], v5, %[whh] offset:48\n\t"
        "global_load_dwordx4 v[222:225], v5, %[whh] offset:64\n\t"
        "global_load_dwordx4 v[226:229], v5, %[whh] offset:80\n\t"
        "global_load_dwordx4 v[230:233], v5, %[whh] offset:96\n\t"
        "global_load_dwordx4 v[234:237], v5, %[whh] offset:112\n\t"
        "global_load_dwordx4 v[238:241], v5, %[whh] offset:128\n\t"
        "global_load_dwordx4 v[242:245], v5, %[whh] offset:144\n\t"
        "global_load_dwordx4 v[246:249], v5, %[whh] offset:160\n\t"
        "global_load_dwordx4 v[250:253], v5, %[whh] offset:176\n\t"
        "global_load_dwordx2 v[254:255], v5, %[whh] offset:192\n\t"
        "s_waitcnt vmcnt(0)\n\t"
        "v_add_f32 v48,  v48,  v7\n\t"            // b = b_ih + b_hh
        "v_add_f32 v100, v100, v8\n\t"
        "v_add_f32 v152, v152, v9\n\t"
        "v_add_f32 v204, v204, v10\n\t"
        "v_cmp_gt_u32 vcc, 50, v0\n\t"            // lane < 50 ?
        "v_cndmask_b32 v46, 0, v46, vcc\n\t"      // wfc (0 for idle lanes)
        "v_mov_b32 v20, %[lb]\n\t"                // lds base / h read addr
        "v_lshl_add_u32 v21, v1, 2, v20\n\t"
        "v_add_u32 v21, 8, v21\n\t"               // hn write addr (h[2+u])
        "v_add_u32 v19, 0x300, v20\n\t"           // xa = &xbuf[pp] (pp=0)
        "s_mov_b32 s21, %[nt]\n\t"
        // ================= trio loop ====================================
        "4:\n\t"
        "v_mov_b32 v16, 0\n\t"                    // c_A
        "v_mov_b32 v17, 0\n\t"                    // c_B
        "v_mov_b32 v18, 0\n\t"                    // c_C
        "v_mov_b32 v5, 0\n\t"
        "v_mov_b32 v6, 1.0\n\t"
        "ds_write_b32 v21, v5\n\t"                // h_A[2+u]=0
        "ds_write_b32 v21, v5 offset:256\n\t"
        "ds_write_b32 v21, v5 offset:512\n\t"
        "ds_write_b32 v20, v6\n\t"                // h_*[0]=1.0
        "ds_write_b32 v20, v6 offset:256\n\t"
        "ds_write_b32 v20, v6 offset:512\n\t"
        "ds_read_b32 v12, v19 offset:0\n\t"       // x[pp], x[pp+1], x[pp+2]
        "ds_read_b32 v13, v19 offset:4\n\t"
        "ds_read_b32 v14, v19 offset:8\n\t"
        "s_waitcnt lgkmcnt(0)\n\t"
        "ds_write_b32 v20, v12 offset:4\n\t"      // h_*[1] = xv(t=0)
        "ds_write_b32 v20, v13 offset:260\n\t"
        "ds_write_b32 v20, v14 offset:516\n\t"
        "v_add_u32 v19, 4, v19\n\t"
        "ds_read_b128 v[0:3],   v20 offset:0\n\t"   // fills g0..g3
        "ds_read_b128 v[4:7],   v20 offset:256\n\t"
        "ds_read_b128 v[8:11],  v20 offset:512\n\t"
        "ds_read_b128 v[12:15], v20 offset:16\n\t"
        "s_mov_b32 s20, 94\n\t"
        // ============== main loop: steps 0..93 for A,B,C ================
        "3:\n\t"
        GRPMX("3", PA, W0,  B0, "ds_read_b128 v[0:3],   v20 offset:272\n\t")
        GRPMX("3", PB, W0,  B1, "ds_read_b128 v[4:7],   v20 offset:528\n\t")
        GRPMX("3", PC, W0,  B2, "ds_read_b128 v[8:11],  v20 offset:32\n\t")
        GRPX("3", PA, W1,  B3, "ds_read_b128 v[12:15], v20 offset:288\n\t")
        GRPX("3", PB, W1,  B0, "ds_read_b128 v[0:3],   v20 offset:544\n\t")
        GRPX("3", PC, W1,  B1, "ds_read_b128 v[4:7],   v20 offset:48\n\t")
        GRPX("3", PA, W2,  B2, "ds_read_b128 v[8:11],  v20 offset:304\n\t")
        GRPX("3", PB, W2,  B3, "ds_read_b128 v[12:15], v20 offset:560\n\t")
        GRPX("3", PC, W2,  B0, "ds_read_b128 v[0:3],   v20 offset:64\n\t")
        GRPX("3", PA, W3,  B1, "ds_read_b128 v[4:7],   v20 offset:320\n\t")
        GRPX("3", PB, W3,  B2, "ds_read_b128 v[8:11],  v20 offset:576\n\t")
        GRPX("3", PC, W3,  B3, "ds_read_b128 v[12:15], v20 offset:80\n\t")
        GRPX("3", PA, W4,  B0, "ds_read_b128 v[0:3],   v20 offset:336\n\t")
        GRPX("3", PB, W4,  B1, "ds_read_b128 v[4:7],   v20 offset:592\n\t")
        GRPX("3", PC, W4,  B2, "ds_read_b128 v[8:11],  v20 offset:96\n\t")
        GRPX("3", PA, W5,  B3, "ds_read_b128 v[12:15], v20 offset:352\n\t")
        GRPX("3", PB, W5,  B0, "ds_read_b128 v[0:3],   v20 offset:608\n\t")
        GRPX("3", PC, W5,  B1, "ds_read_b128 v[4:7],   v20 offset:112\n\t")
        GRPX("3", PA, W6,  B2, "ds_read_b128 v[8:11],  v20 offset:368\n\t")
        GRPX("3", PB, W6,  B3, "ds_read_b128 v[12:15], v20 offset:624\n\t")
        GRPX("3", PC, W6,  B0, "ds_read_b128 v[0:3],   v20 offset:128\n\t")
        GRPX("3", PA, W7,  B1, "ds_read_b128 v[4:7],   v20 offset:384\n\t")
        GRPX("3", PB, W7,  B2, "ds_read_b128 v[8:11],  v20 offset:640\n\t")
        GRPX("3", PC, W7,  B3, "ds_read_b128 v[12:15], v20 offset:144\n\t")
        GRPX("3", PA, W8,  B0, "ds_read_b128 v[0:3],   v20 offset:400\n\t")
        GRPX("3", PB, W8,  B1, "ds_read_b128 v[4:7],   v20 offset:656\n\t")
        GRPX("3", PC, W8,  B2, "ds_read_b128 v[8:11],  v20 offset:160\n\t")
        GRPX("3", PA, W9,  B3, "ds_read_b128 v[12:15], v20 offset:416\n\t")
        GRPX("3", PB, W9,  B0, "ds_read_b128 v[0:3],   v20 offset:672\n\t")
        GRPX("3", PC, W9,  B1, "ds_read_b128 v[4:7],   v20 offset:176\n\t")
        GRPX("3", PA, W10, B2, "ds_read_b128 v[8:11],  v20 offset:432\n\t")
        GRPX("3", PB, W10, B3, "ds_read_b128 v[12:15], v20 offset:688\n\t")
        GRPX("3", PC, W10, B0, "ds_read_b128 v[0:3],   v20 offset:192\n\t")
        GRPX("3", PA, W11, B1, "ds_read_b128 v[4:7],   v20 offset:448\n\t")
        GRPX("3", PB, W11, B2, "ds_read_b128 v[8:11],  v20 offset:704\n\t")
        GRPX("3", PC, W11, B3, "")
        // prefetch next-step x for A,B,C (counted in g36-38 waits)
        "ds_read_b32 v12, v19 offset:0\n\t"
        "ds_read_b32 v13, v19 offset:4\n\t"
        "ds_read_b32 v14, v19 offset:8\n\t"
        GRPX("5", PA, W12, B0, "")
        GRPX("4", PB, W12, B1, "")
        GRPX("3", PC, W12, B2, "")
        // ---- folds ----
        "v_add_f32 v22, v22, v23\n\t" "v_add_f32 v24, v24, v25\n\t"
        "v_add_f32 v26, v26, v27\n\t" "v_add_f32 v28, v28, v29\n\t"
        "v_add_f32 v30, v30, v31\n\t" "v_add_f32 v32, v32, v33\n\t"
        "v_add_f32 v34, v34, v35\n\t" "v_add_f32 v36, v36, v37\n\t"
        "v_add_f32 v38, v38, v39\n\t" "v_add_f32 v40, v40, v41\n\t"
        "v_add_f32 v42, v42, v43\n\t" "v_add_f32 v44, v44, v45\n\t"
        // ---- 3-way interleaved activation tail ----
        "v_mul_f32 v23, 0xbfb8aa3b, v22\n\t"
        "v_mul_f32 v31, 0xbfb8aa3b, v30\n\t"
        "v_mul_f32 v39, 0xbfb8aa3b, v38\n\t"
        "v_mul_f32 v25, 0xbfb8aa3b, v24\n\t"
        "v_mul_f32 v33, 0xbfb8aa3b, v32\n\t"
        "v_mul_f32 v41, 0xbfb8aa3b, v40\n\t"
        "v_mul_f32 v27, 0x4038aa3b, v26\n\t"
        "v_mul_f32 v35, 0x4038aa3b, v34\n\t"
        "v_mul_f32 v43, 0x4038aa3b, v42\n\t"
        "v_mul_f32 v29, 0xbfb8aa3b, v28\n\t"
        "v_mul_f32 v37, 0xbfb8aa3b, v36\n\t"
        "v_mul_f32 v45, 0xbfb8aa3b, v44\n\t"
        "v_exp_f32 v23, v23\n\t" "v_exp_f32 v31, v31\n\t" "v_exp_f32 v39, v39\n\t"
        "v_exp_f32 v25, v25\n\t" "v_exp_f32 v33, v33\n\t" "v_exp_f32 v41, v41\n\t"
        "v_exp_f32 v27, v27\n\t" "v_exp_f32 v35, v35\n\t" "v_exp_f32 v43, v43\n\t"
        "v_exp_f32 v29, v29\n\t" "v_exp_f32 v37, v37\n\t" "v_exp_f32 v45, v45\n\t"
        "v_add_f32 v23, 1.0, v23\n\t" "v_add_f32 v31, 1.0, v31\n\t" "v_add_f32 v39, 1.0, v39\n\t"
        "v_add_f32 v25, 1.0, v25\n\t" "v_add_f32 v33, 1.0, v33\n\t" "v_add_f32 v41, 1.0, v41\n\t"
        "v_add_f32 v27, 1.0, v27\n\t" "v_add_f32 v35, 1.0, v35\n\t" "v_add_f32 v43, 1.0, v43\n\t"
        "v_add_f32 v29, 1.0, v29\n\t" "v_add_f32 v37, 1.0, v37\n\t" "v_add_f32 v45, 1.0, v45\n\t"
        "v_rcp_f32 v23, v23\n\t" "v_rcp_f32 v31, v31\n\t" "v_rcp_f32 v39, v39\n\t"
        "v_rcp_f32 v25, v25\n\t" "v_rcp_f32 v33, v33\n\t" "v_rcp_f32 v41, v41\n\t"
        "v_rcp_f32 v27, v27\n\t" "v_rcp_f32 v35, v35\n\t" "v_rcp_f32 v43, v43\n\t"
        "v_rcp_f32 v29, v29\n\t" "v_rcp_f32 v37, v37\n\t" "v_rcp_f32 v45, v45\n\t"
        "v_fma_f32 v27, -2.0, v27, 1.0\n\t"
        "v_fma_f32 v35, -2.0, v35, 1.0\n\t"
        "v_fma_f32 v43, -2.0, v43, 1.0\n\t"
        "v_mul_f32 v22, v23, v27\n\t"
        "v_mul_f32 v30, v31, v35\n\t"
        "v_mul_f32 v38, v39, v43\n\t"
        "v_fma_f32 v16, v25, v16, v22\n\t"
        "v_fma_f32 v17, v33, v17, v30\n\t"
        "v_fma_f32 v18, v41, v18, v38\n\t"
        "v_mul_f32 v24, 0x4038aa3b, v16\n\t"
        "v_mul_f32 v32, 0x4038aa3b, v17\n\t"
        "v_mul_f32 v40, 0x4038aa3b, v18\n\t"
        "v_exp_f32 v24, v24\n\t" "v_exp_f32 v32, v32\n\t" "v_exp_f32 v40, v40\n\t"
        "v_add_f32 v24, 1.0, v24\n\t" "v_add_f32 v32, 1.0, v32\n\t" "v_add_f32 v40, 1.0, v40\n\t"
        "v_rcp_f32 v24, v24\n\t" "v_rcp_f32 v32, v32\n\t" "v_rcp_f32 v40, v40\n\t"
        "s_nop 0\n\t"
        "v_fma_f32 v24, -2.0, v24, 1.0\n\t"
        "v_fma_f32 v32, -2.0, v32, 1.0\n\t"
        "v_fma_f32 v40, -2.0, v40, 1.0\n\t"
        "v_mul_f32 v22, v29, v24\n\t"            // hn_A
        "v_mul_f32 v30, v37, v32\n\t"            // hn_B
        "v_mul_f32 v38, v45, v40\n\t"            // hn_C
        "ds_write_b32 v21, v22\n\t"
        "ds_write_b32 v21, v30 offset:256\n\t"
        "ds_write_b32 v21, v38 offset:512\n\t"
        "s_waitcnt lgkmcnt(3)\n\t"               // xv prefetches done
        "ds_write_b32 v20, v12 offset:4\n\t"
        "ds_write_b32 v20, v13 offset:260\n\t"
        "ds_write_b32 v20, v14 offset:516\n\t"
        "v_add_u32 v19, 4, v19\n\t"
        "ds_read_b128 v[0:3],   v20 offset:0\n\t"
        "ds_read_b128 v[4:7],   v20 offset:256\n\t"
        "ds_read_b128 v[8:11],  v20 offset:512\n\t"
        "ds_read_b128 v[12:15], v20 offset:16\n\t"
        "s_sub_u32 s20, s20, 1\n\t"
        "s_cmp_lg_u32 s20, 0\n\t"
        "s_cbranch_scc1 3b\n\t"
        // ============== epilogue: serialized pred chain =================
        "s_waitcnt lgkmcnt(0)\n\t"
        "v_add_u32 v19, -8, v19\n\t"             // base = &xbuf[pp+93]
        SOLOX("4",  "4",   "v16", "0",   HA)     // A step94
        SOLOX("8",  "4",   "v16", "0",   HA)     // A step95
        FC("12")                                 // pred[pp]
        SOLOX("8",  "260", "v17", "256", HB)     // B step94
        SOLOX("12", "260", "v17", "256", HB)     // B step95 (xv=pred[pp])
        FC("16")                                 // pred[pp+1]
        SOLOX("12", "516", "v18", "512", HC)     // C step94 (xv=pred[pp])
        SOLOX("16", "516", "v18", "512", HC)     // C step95 (xv=pred[pp+1])
        FC("20")                                 // pred[pp+2]
        "s_waitcnt lgkmcnt(0)\n\t"
        "v_add_u32 v19, 0xfffffe98, v19\n\t"     // -360: xa -> &xbuf[pp+3]
        "s_sub_u32 s21, s21, 1\n\t"
        "s_cmp_lg_u32 s21, 0\n\t"
        "s_cbranch_scc1 4b\n\t"
        :
        : [lb] "v"(lb), [nt] "s"(nt),
          [whh] "s"(W_hh), [wih] "s"(W_ih), [bih] "s"(b_ih), [bhh] "s"(b_hh),
          [wfcp] "s"(W_fc), [bfcp] "s"(b_fc)
        : "memory", "scc", "vcc", "s20", "s21", "s22", "s25", "s26", "s27",
          "v0","v1","v2","v3","v4","v5","v6","v7","v8","v9","v10","v11",
          "v12","v13","v14","v15","v16","v17","v18","v19","v20","v21","v22",
          "v23","v24","v25","v26","v27","v28","v29","v30","v31","v32","v33",
          "v34","v35","v36","v37","v38","v39","v40","v41","v42","v43","v44",
          "v45","v46",
          "v48","v49","v50","v51","v52","v53","v54","v55","v56","v57","v58",
          "v59","v60","v61","v62","v63","v64","v65","v66","v67","v68","v69",
          "v70","v71","v72","v73","v74","v75","v76","v77","v78","v79","v80",
          "v81","v82","v83","v84","v85","v86","v87","v88","v89","v90","v91",
          "v92","v93","v94","v95","v96","v97","v98","v99","v100","v101",
          "v102","v103","v104","v105","v106","v107","v108","v109","v110",
          "v111","v112","v113","v114","v115","v116","v117","v118","v119",
          "v120","v121","v122","v123","v124","v125","v126","v127","v128",
          "v129","v130","v131","v132","v133","v134","v135","v136","v137",
          "v138","v139","v140","v141","v142","v143","v144","v145","v146",
          "v147","v148","v149","v150","v151","v152","v153","v154","v155",
          "v156","v157","v158","v159","v160","v161","v162","v163","v164",
          "v165","v166","v167","v168","v169","v170","v171","v172","v173",
          "v174","v175","v176","v177","v178","v179","v180","v181","v182",
          "v183","v184","v185","v186","v187","v188","v189","v190","v191",
          "v192","v193","v194","v195","v196","v197","v198","v199","v200",
          "v201","v202","v203","v204","v205","v206","v207","v208","v209",
          "v210","v211","v212","v213","v214","v215","v216","v217","v218",
          "v219","v220","v221","v222","v223","v224","v225","v226","v227",
          "v228","v229","v230","v231","v232","v233","v234","v235","v236",
          "v237","v238","v239","v240","v241","v242","v243","v244","v245",
          "v246","v247","v248","v249","v250","v251","v252","v253","v254",
          "v255");

    if (j < NP) out[b * NP + j] = lds[192 + TLEN + j];
}

extern "C" void kernel_launch(void* const* d_in, const int* in_sizes, int n_in,
                              void* d_out, int out_size, void* d_ws, size_t ws_size,
                              hipStream_t stream)
{
    const float* x    = (const float*)d_in[0];
    const float* W_ih = (const float*)d_in[1];
    const float* W_hh = (const float*)d_in[2];
    const float* b_ih = (const float*)d_in[3];
    const float* b_hh = (const float*)d_in[4];
    const float* W_fc = (const float*)d_in[5];
    const float* b_fc = (const float*)d_in[6];
    const int*   np   = (const int*)d_in[7];
    float* out = (float*)d_out;

    const int B = in_sizes[0] / TLEN;   // 1024
    rec_lstm_kernel<<<B, 64, 0, stream>>>(x, W_ih, W_hh, b_ih, b_hh,
                                          W_fc, b_fc, np, out);
}